// Round 3
// baseline (595.572 us; speedup 1.0000x reference)
//
#include <hip/hip_runtime.h>
#include <hip/hip_bf16.h>

typedef __attribute__((ext_vector_type(8))) short short8;
typedef __attribute__((ext_vector_type(4))) float f32x4;
typedef __attribute__((ext_vector_type(16))) float f32x16;

#define WS_PART 0u            // 256 * float2 partials
#define WS_STATS 4096u        // 8 * float2 (mean, rstd)
#define WS_WT 8192u           // 4*256*256 bf16 = 512KB, ends 532480
#define WS_ML 532480u         // 2*32768 float2 = 512KB, ends 1056768
#define WS_Q  2097152u
#define WS_K  (WS_Q + 16777216u)
#define WS_V  (WS_K + 16777216u)   // reused as attention partial-0 after k_vt
#define WS_VT (WS_V + 16777216u)
#define WS_O  (WS_VT + 16777216u)  // reused as attention partial-1

__device__ __forceinline__ unsigned short f2bf(float f) {
  unsigned int u = __builtin_bit_cast(unsigned int, f);
  u += 0x7fffu + ((u >> 16) & 1u);
  return (unsigned short)(u >> 16);
}
__device__ __forceinline__ float bf2f(unsigned short h) {
  unsigned int u = ((unsigned int)h) << 16;
  return __builtin_bit_cast(float, u);
}

__device__ __forceinline__ void gl_lds16(const unsigned short* g, unsigned short* l) {
  __builtin_amdgcn_global_load_lds(
      (const __attribute__((address_space(1))) unsigned int*)g,
      (__attribute__((address_space(3))) unsigned int*)l, 16, 0, 0);
}

__device__ __forceinline__ unsigned int cvtpk(float lo, float hi) {
  unsigned int r;
  asm("v_cvt_pk_bf16_f32 %0, %1, %2" : "=v"(r) : "v"(lo), "v"(hi));
  return r;
}

// ---------------- weight transpose: wT[m][d][c] = bf16(w_m[c][d]) ----------------
__global__ void k_wt(const float* __restrict__ wq, const float* __restrict__ wk,
                     const float* __restrict__ wv, const float* __restrict__ wp,
                     unsigned short* __restrict__ wT) {
  int m = blockIdx.x >> 8;
  int c = blockIdx.x & 255;
  const float* w = (m == 0) ? wq : (m == 1) ? wk : (m == 2) ? wv : wp;
  int d = threadIdx.x;
  wT[(size_t)(m * 256 + d) * 256 + c] = f2bf(w[c * 256 + d]);
}

// ---------------- GroupNorm stats (per batch over 1M elements) ----------------
__global__ void k_gn_part(const float* __restrict__ x, float2* __restrict__ part) {
  int b = blockIdx.x >> 5, seg = blockIdx.x & 31;
  const float4* xp = (const float4*)(x + ((size_t)b << 20) + ((size_t)seg << 15));
  float s = 0.f, sq = 0.f;
  for (int i = 0; i < 32; ++i) {
    float4 v = xp[threadIdx.x + i * 256];
    s += v.x + v.y + v.z + v.w;
    sq += v.x * v.x + v.y * v.y + v.z * v.z + v.w * v.w;
  }
  for (int m = 1; m <= 32; m <<= 1) { s += __shfl_xor(s, m); sq += __shfl_xor(sq, m); }
  __shared__ float2 red[4];
  int w = threadIdx.x >> 6;
  if ((threadIdx.x & 63) == 0) red[w] = make_float2(s, sq);
  __syncthreads();
  if (threadIdx.x == 0) {
    float S = 0.f, Q = 0.f;
    for (int i = 0; i < 4; ++i) { S += red[i].x; Q += red[i].y; }
    part[blockIdx.x] = make_float2(S, Q);
  }
}

__global__ void k_gn_stats(const float2* __restrict__ part, float2* __restrict__ stats) {
  int b = blockIdx.x, t = threadIdx.x;
  float s = 0.f, sq = 0.f;
  if (t < 32) { float2 p = part[b * 32 + t]; s = p.x; sq = p.y; }
  for (int m = 1; m <= 32; m <<= 1) { s += __shfl_xor(s, m); sq += __shfl_xor(sq, m); }
  if (t == 0) {
    float mean = s * (1.f / 1048576.f);
    float var = sq * (1.f / 1048576.f) - mean * mean;
    stats[b] = make_float2(mean, rsqrtf(var + 1e-3f));
  }
}

// ---------------- fused GN + QKV projection GEMM ----------------
__global__ __launch_bounds__(256) void k_qkv(
    const float* __restrict__ x, const float* __restrict__ gamma, const float* __restrict__ beta,
    const float* __restrict__ bq, const float* __restrict__ bk, const float* __restrict__ bv,
    const float2* __restrict__ stats, const unsigned short* __restrict__ wT,
    unsigned short* __restrict__ qo, unsigned short* __restrict__ ko, unsigned short* __restrict__ vo)
{
  __shared__ unsigned short As[128 * 64];
  __shared__ unsigned short Bs[128 * 64];
  const int bm = blockIdx.x, bn = blockIdx.y;
  const int mat = bn >> 1, dbase = (bn & 1) * 128;
  const int tid = threadIdx.x, lane = tid & 63, w = tid >> 6;
  const int wm = w >> 1, wn = w & 1;
  const int m0 = bm * 128;
  const float2 st = stats[bm >> 5];
  f32x16 acc[2][2] = {};
  for (int ks = 0; ks < 4; ++ks) {
    for (int i = 0; i < 8; ++i) {
      int chunk = tid + i * 256;
      int row = chunk >> 4, cq = (chunk & 15) * 4;
      int c = ks * 64 + cq;
      const float4 xv = *(const float4*)(x + (size_t)(m0 + row) * 256 + c);
      const float4 g = *(const float4*)(gamma + c);
      const float4 bt = *(const float4*)(beta + c);
      unsigned short h[4];
      h[0] = f2bf((xv.x - st.x) * st.y * g.x + bt.x);
      h[1] = f2bf((xv.y - st.x) * st.y * g.y + bt.y);
      h[2] = f2bf((xv.z - st.x) * st.y * g.z + bt.z);
      h[3] = f2bf((xv.w - st.x) * st.y * g.w + bt.w);
      *(uint2*)(&As[row * 64 + (cq ^ ((row & 7) << 3))]) = *(uint2*)h;
    }
    for (int i = 0; i < 4; ++i) {
      int chunk = tid + i * 256;
      int row = chunk >> 3, cc = (chunk & 7) * 8;
      const uint4* src = (const uint4*)(wT + (size_t)(mat * 256 + dbase + row) * 256 + ks * 64 + cc);
      *(uint4*)(&Bs[row * 64 + (cc ^ ((row & 7) << 3))]) = *src;
    }
    __syncthreads();
    for (int kk = 0; kk < 4; ++kk) {
      short8 a[2], b[2];
      for (int mi = 0; mi < 2; ++mi) {
        int row = wm * 64 + mi * 32 + (lane & 31);
        int off = (kk * 16 + (lane >> 5) * 8) ^ ((row & 7) << 3);
        a[mi] = *(const short8*)(&As[row * 64 + off]);
      }
      for (int ni = 0; ni < 2; ++ni) {
        int row = wn * 64 + ni * 32 + (lane & 31);
        int off = (kk * 16 + (lane >> 5) * 8) ^ ((row & 7) << 3);
        b[ni] = *(const short8*)(&Bs[row * 64 + off]);
      }
      for (int mi = 0; mi < 2; ++mi)
        for (int ni = 0; ni < 2; ++ni)
          acc[mi][ni] = __builtin_amdgcn_mfma_f32_32x32x16_bf16(a[mi], b[ni], acc[mi][ni], 0, 0, 0);
    }
    __syncthreads();
  }
  const float* bias = (mat == 0) ? bq : (mat == 1) ? bk : bv;
  unsigned short* outp = (mat == 0) ? qo : (mat == 1) ? ko : vo;
  const float qs = 0.09016844005555646f;  // (1/16) * log2(e)
  for (int ni = 0; ni < 2; ++ni) {
    int dcol = dbase + wn * 64 + ni * 32 + (lane & 31);
    float bv_ = bias[dcol];
    for (int mi = 0; mi < 2; ++mi)
      for (int r = 0; r < 16; ++r) {
        int rowD = (r & 3) + 8 * (r >> 2) + 4 * (lane >> 5);
        int token = m0 + wm * 64 + mi * 32 + rowD;
        float v = acc[mi][ni][r] + bv_;
        if (mat == 0) v *= qs;
        outp[(size_t)token * 256 + dcol] = f2bf(v);
      }
  }
}

// ---------------- V transpose: vt[b][d][n] = v[b][n][d] ----------------
__global__ __launch_bounds__(256) void k_vt(const unsigned short* __restrict__ v,
                                            unsigned short* __restrict__ vt) {
  __shared__ unsigned short T[64 * 64];
  int bx = blockIdx.x;
  int batch = bx >> 8;
  int tn = (bx & 255) >> 2, td = bx & 3;
  int n0 = tn * 64, d0 = td * 64;
  int tid = threadIdx.x;
  for (int i = 0; i < 2; ++i) {
    int chunk = tid + i * 256;
    int r = chunk >> 3, cc = (chunk & 7) * 8;
    const uint4* src = (const uint4*)(v + (size_t)(batch * 4096 + n0 + r) * 256 + d0 + cc);
    *(uint4*)(&T[r * 64 + (cc ^ ((r & 7) << 3))]) = *src;
  }
  __syncthreads();
  for (int i = 0; i < 2; ++i) {
    int chunk = tid + i * 256;
    int rd = chunk >> 3, cn = (chunk & 7) * 8;
    unsigned short tmp[8];
    for (int j = 0; j < 8; ++j) {
      int nn = cn + j;
      tmp[j] = T[nn * 64 + (rd ^ ((nn & 7) << 3))];
    }
    *(uint4*)(vt + (size_t)(batch * 256 + d0 + rd) * 4096 + n0 + cn) = *(uint4*)tmp;
  }
}

// ---------------- flash attention, kv-split ----------------
// 1024 blocks, ALL co-resident (4/CU): g=blockIdx&15 -> (batch,half) pinned per XCD,
// qt=blockIdx>>4 (64 q rows). 4 waves x 16 q-rows. KVBLK=32, 64 iters per half.
// Swapped QK^T: S^T = mfma(K,Q) -> q on lane&15, kv on regs; softmax row-local;
// P -> PV A-frag in-register via cvt_pk_bf16 + ds_bpermute. Unnormalized bf16
// partials + (m,l) per half; k_merge combines.
__global__ __launch_bounds__(256, 4) void k_attn(
    const unsigned short* __restrict__ q, const unsigned short* __restrict__ k,
    const unsigned short* __restrict__ vt,
    unsigned short* __restrict__ part0, unsigned short* __restrict__ part1,
    float2* __restrict__ ml)
{
  __shared__ unsigned short Ks[32 * 256];  // K tile (content swizzled via source)
  __shared__ unsigned short Vt[256 * 32];  // V^T tile (content swizzled via source)
  const int g = blockIdx.x & 15, qt = blockIdx.x >> 4;
  const int batch = g >> 1, half = g & 1;
  const int q0 = qt * 64;
  const int tid = threadIdx.x, lane = tid & 63, li = lane & 15, hi = lane >> 4, w = tid >> 6;
  const size_t qtok = (size_t)(batch * 4096 + q0 + w * 16 + li);
  short8 qf[8];
  for (int kt = 0; kt < 8; ++kt)
    qf[kt] = *(const short8*)(q + qtok * 256 + kt * 32 + hi * 8);
  f32x4 acc[16] = {};
  float m_r = -INFINITY, l_r = 0.f;
  // bpermute source-lane indices (bytes): pull from lane ((2*hi+b)&3)*16+li
  const int idx0 = ((((hi << 1) + 0) & 3) * 16 + li) << 2;
  const int idx1 = ((((hi << 1) + 1) & 3) * 16 + li) << 2;

  const unsigned short* kb = k + ((size_t)batch * 4096 + half * 2048) * 256;
  const unsigned short* vb = vt + (size_t)batch * 256 * 4096 + half * 2048;

#define STAGE() do {                                                        \
    _Pragma("unroll")                                                       \
    for (int i = 0; i < 4; ++i) {                                           \
      int krow = w * 8 + i * 2 + (lane >> 5);                               \
      gl_lds16(kb + krow * 256 + ((((lane & 31) ^ (krow & 7))) << 3),       \
               &Ks[(w * 8 + i * 2) * 256]);                                 \
    }                                                                       \
    _Pragma("unroll")                                                       \
    for (int i = 0; i < 4; ++i) {                                           \
      int vrow = w * 64 + i * 16 + (lane >> 2);                             \
      gl_lds16(vb + (size_t)vrow * 4096 + (((lane & 3) ^ (vrow & 3)) << 3), \
               &Vt[(w * 64 + i * 16) * 32]);                                \
    }                                                                       \
  } while (0)

  STAGE();
  for (int it = 0; it < 64; ++it) {
    __syncthreads();  // staging visible
    // S^T = K Q^T : s[ct][r] = S[kv=ct*16+hi*4+r][q=li]
    f32x4 s[2] = {};
    __builtin_amdgcn_s_setprio(1);
    for (int ct = 0; ct < 2; ++ct)
      for (int kt = 0; kt < 8; ++kt) {
        int rowK = ct * 16 + li;
        int off = (kt * 32 + hi * 8) ^ ((li & 7) << 3);
        short8 kf = *(const short8*)(&Ks[rowK * 256 + off]);
        s[ct] = __builtin_amdgcn_mfma_f32_16x16x32_bf16(kf, qf[kt], s[ct], 0, 0, 0);
      }
    __builtin_amdgcn_s_setprio(0);
    // row-local softmax (q = li for this lane)
    float pm = fmaxf(fmaxf(fmaxf(s[0][0], s[0][1]), fmaxf(s[0][2], s[0][3])),
                     fmaxf(fmaxf(s[1][0], s[1][1]), fmaxf(s[1][2], s[1][3])));
    pm = fmaxf(pm, __shfl_xor(pm, 16));
    pm = fmaxf(pm, __shfl_xor(pm, 32));
    if (!__all(pm - m_r <= 8.0f)) {  // defer-max (T13)
      float mn = fmaxf(m_r, pm);
      float corr = exp2f(m_r - mn);
      m_r = mn;
      l_r *= corr;
      float cq[4];
      for (int r = 0; r < 4; ++r) cq[r] = __shfl(corr, hi * 4 + r);
      for (int dt = 0; dt < 16; ++dt)
        for (int r = 0; r < 4; ++r) acc[dt][r] *= cq[r];
    }
    float rs = 0.f;
    for (int ct = 0; ct < 2; ++ct)
      for (int r = 0; r < 4; ++r) {
        float p = exp2f(s[ct][r] - m_r);
        s[ct][r] = p;
        rs += p;
      }
    rs += __shfl_xor(rs, 16);
    rs += __shfl_xor(rs, 32);
    l_r += rs;
    // pack P to bf16 pairs and exchange into PV A-fragment layout
    unsigned int pk00 = cvtpk(s[0][0], s[0][1]), pk01 = cvtpk(s[0][2], s[0][3]);
    unsigned int pk10 = cvtpk(s[1][0], s[1][1]), pk11 = cvtpk(s[1][2], s[1][3]);
    int w0a = __builtin_amdgcn_ds_bpermute(idx0, (int)pk00);
    int w0b = __builtin_amdgcn_ds_bpermute(idx0, (int)pk10);
    int w1a = __builtin_amdgcn_ds_bpermute(idx0, (int)pk01);
    int w1b = __builtin_amdgcn_ds_bpermute(idx0, (int)pk11);
    int w2a = __builtin_amdgcn_ds_bpermute(idx1, (int)pk00);
    int w2b = __builtin_amdgcn_ds_bpermute(idx1, (int)pk10);
    int w3a = __builtin_amdgcn_ds_bpermute(idx1, (int)pk01);
    int w3b = __builtin_amdgcn_ds_bpermute(idx1, (int)pk11);
    bool sel = (lane & 32) != 0;
    int4 pw = { sel ? w0b : w0a, sel ? w1b : w1a, sel ? w2b : w2a, sel ? w3b : w3a };
    short8 pf = __builtin_bit_cast(short8, pw);
    // O += P V : acc[dt] over d = dt*16+li, q = hi*4+r
    __builtin_amdgcn_s_setprio(1);
    for (int dt = 0; dt < 16; ++dt) {
      int rowd = dt * 16 + li;
      int off = (hi * 8) ^ ((li & 3) << 3);
      short8 vf = *(const short8*)(&Vt[rowd * 32 + off]);
      acc[dt] = __builtin_amdgcn_mfma_f32_16x16x32_bf16(pf, vf, acc[dt], 0, 0, 0);
    }
    __builtin_amdgcn_s_setprio(0);
    __syncthreads();  // reads done before restage
    if (it < 63) {
      kb += 32 * 256;
      vb += 32;
      STAGE();
    }
  }
#undef STAGE
  // write (m,l) from lanes 0..15 (q = lane)
  if (lane < 16)
    ml[half * 32768 + (size_t)batch * 4096 + q0 + w * 16 + lane] = make_float2(m_r, l_r);
  // write unnormalized partial O
  unsigned short* pout = (half ? part1 : part0) + ((size_t)batch * 4096 + q0 + w * 16) * 256;
  for (int dt = 0; dt < 16; ++dt)
    for (int r = 0; r < 4; ++r)
      pout[(size_t)(hi * 4 + r) * 256 + dt * 16 + li] = f2bf(acc[dt][r]);
}

// ---------------- merge kv-split halves ----------------
__global__ __launch_bounds__(256) void k_merge(
    const unsigned short* __restrict__ p0, const unsigned short* __restrict__ p1,
    const float2* __restrict__ ml, unsigned short* __restrict__ o)
{
  int tid = threadIdx.x;
  int tok = blockIdx.x * 8 + (tid >> 5);
  int d0 = (tid & 31) * 8;
  float2 a = ml[tok];
  float2 b = ml[32768 + tok];
  float m = fmaxf(a.x, b.x);
  float s0 = exp2f(a.x - m), s1 = exp2f(b.x - m);
  float r0 = s0 / (s0 * a.y + s1 * b.y);
  float r1 = s1 / (s0 * a.y + s1 * b.y);
  short8 u0 = *(const short8*)(p0 + (size_t)tok * 256 + d0);
  short8 u1 = *(const short8*)(p1 + (size_t)tok * 256 + d0);
  unsigned short r[8];
  for (int j = 0; j < 8; ++j)
    r[j] = f2bf(r0 * bf2f((unsigned short)u0[j]) + r1 * bf2f((unsigned short)u1[j]));
  *(short8*)(o + (size_t)tok * 256 + d0) = *(short8*)r;
}

// ---------------- output projection + bias + residual ----------------
__global__ __launch_bounds__(256) void k_proj(
    const unsigned short* __restrict__ o, const unsigned short* __restrict__ wT,
    const float* __restrict__ bp, const float* __restrict__ x, float* __restrict__ out)
{
  __shared__ unsigned short As[128 * 64];
  __shared__ unsigned short Bs[128 * 64];
  const int bm = blockIdx.x, bn = blockIdx.y;
  const int dbase = bn * 128;
  const int tid = threadIdx.x, lane = tid & 63, w = tid >> 6;
  const int wm = w >> 1, wn = w & 1;
  const int m0 = bm * 128;
  f32x16 acc[2][2] = {};
  for (int ks = 0; ks < 4; ++ks) {
    for (int i = 0; i < 4; ++i) {
      int chunk = tid + i * 256;
      int row = chunk >> 3, cc = (chunk & 7) * 8;
      const uint4* src = (const uint4*)(o + (size_t)(m0 + row) * 256 + ks * 64 + cc);
      *(uint4*)(&As[row * 64 + (cc ^ ((row & 7) << 3))]) = *src;
    }
    for (int i = 0; i < 4; ++i) {
      int chunk = tid + i * 256;
      int row = chunk >> 3, cc = (chunk & 7) * 8;
      const uint4* src = (const uint4*)(wT + (size_t)(3 * 256 + dbase + row) * 256 + ks * 64 + cc);
      *(uint4*)(&Bs[row * 64 + (cc ^ ((row & 7) << 3))]) = *src;
    }
    __syncthreads();
    for (int kk = 0; kk < 4; ++kk) {
      short8 a[2], b[2];
      for (int mi = 0; mi < 2; ++mi) {
        int row = wm * 64 + mi * 32 + (lane & 31);
        int off = (kk * 16 + (lane >> 5) * 8) ^ ((row & 7) << 3);
        a[mi] = *(const short8*)(&As[row * 64 + off]);
      }
      for (int ni = 0; ni < 2; ++ni) {
        int row = wn * 64 + ni * 32 + (lane & 31);
        int off = (kk * 16 + (lane >> 5) * 8) ^ ((row & 7) << 3);
        b[ni] = *(const short8*)(&Bs[row * 64 + off]);
      }
      for (int mi = 0; mi < 2; ++mi)
        for (int ni = 0; ni < 2; ++ni)
          acc[mi][ni] = __builtin_amdgcn_mfma_f32_32x32x16_bf16(a[mi], b[ni], acc[mi][ni], 0, 0, 0);
    }
    __syncthreads();
  }
  for (int ni = 0; ni < 2; ++ni) {
    int dcol = dbase + wn * 64 + ni * 32 + (lane & 31);
    float bv_ = bp[dcol];
    for (int mi = 0; mi < 2; ++mi)
      for (int r = 0; r < 16; ++r) {
        int rowD = (r & 3) + 8 * (r >> 2) + 4 * (lane >> 5);
        size_t idx = (size_t)(m0 + wm * 64 + mi * 32 + rowD) * 256 + dcol;
        out[idx] = x[idx] + acc[mi][ni][r] + bv_;
      }
  }
}

extern "C" void kernel_launch(void* const* d_in, const int* in_sizes, int n_in,
                              void* d_out, int out_size, void* d_ws, size_t ws_size,
                              hipStream_t stream) {
  const float* x = (const float*)d_in[0];
  const float* gamma = (const float*)d_in[1];
  const float* beta = (const float*)d_in[2];
  const float* wq = (const float*)d_in[3];
  const float* bq = (const float*)d_in[4];
  const float* wk = (const float*)d_in[5];
  const float* bk = (const float*)d_in[6];
  const float* wv = (const float*)d_in[7];
  const float* bv = (const float*)d_in[8];
  const float* wp = (const float*)d_in[9];
  const float* bp = (const float*)d_in[10];
  char* ws = (char*)d_ws;
  float2* part = (float2*)(ws + WS_PART);
  float2* stats = (float2*)(ws + WS_STATS);
  unsigned short* wT = (unsigned short*)(ws + WS_WT);
  float2* mlw = (float2*)(ws + WS_ML);
  unsigned short* qw = (unsigned short*)(ws + WS_Q);
  unsigned short* kw = (unsigned short*)(ws + WS_K);
  unsigned short* vw = (unsigned short*)(ws + WS_V);
  unsigned short* vtw = (unsigned short*)(ws + WS_VT);
  unsigned short* ow = (unsigned short*)(ws + WS_O);
  float* out = (float*)d_out;

  k_wt<<<1024, 256, 0, stream>>>(wq, wk, wv, wp, wT);
  k_gn_part<<<256, 256, 0, stream>>>(x, part);
  k_gn_stats<<<8, 64, 0, stream>>>(part, stats);
  k_qkv<<<dim3(256, 6), 256, 0, stream>>>(x, gamma, beta, bq, bk, bv, stats, wT, qw, kw, vw);
  k_vt<<<2048, 256, 0, stream>>>(vw, vtw);
  // partial0 overwrites V (dead after k_vt), partial1 overwrites O region
  k_attn<<<1024, 256, 0, stream>>>(qw, kw, vtw, vw, ow, mlw);
  // merged O overwrites Q (dead after k_attn)
  k_merge<<<4096, 256, 0, stream>>>(vw, ow, mlw, qw);
  k_proj<<<dim3(256, 2), 256, 0, stream>>>(qw, wT, bp, x, out);
}

// Round 4
// 275.897 us; speedup vs baseline: 2.1587x; 2.1587x over previous
//
#include <hip/hip_runtime.h>
#include <hip/hip_bf16.h>

typedef __attribute__((ext_vector_type(8))) short short8;
typedef __attribute__((ext_vector_type(4))) float f32x4;
typedef __attribute__((ext_vector_type(16))) float f32x16;

#define WS_PART 0u            // 256 * float2 partials
#define WS_STATS 4096u        // 8 * float2 (mean, rstd)
#define WS_WT 8192u           // 4*256*256 bf16 = 512KB, ends 532480
#define WS_ML 532480u         // 2*32768 float2 = 512KB, ends 1056768
#define WS_Q  2097152u
#define WS_K  (WS_Q + 16777216u)
#define WS_V  (WS_K + 16777216u)   // reused as attention partial-0 after k_vt
#define WS_VT (WS_V + 16777216u)
#define WS_O  (WS_VT + 16777216u)  // reused as attention partial-1

__device__ __forceinline__ unsigned short f2bf(float f) {
  unsigned int u = __builtin_bit_cast(unsigned int, f);
  u += 0x7fffu + ((u >> 16) & 1u);
  return (unsigned short)(u >> 16);
}
__device__ __forceinline__ float bf2f(unsigned short h) {
  unsigned int u = ((unsigned int)h) << 16;
  return __builtin_bit_cast(float, u);
}

__device__ __forceinline__ void gl_lds16(const unsigned short* g, unsigned short* l) {
  __builtin_amdgcn_global_load_lds(
      (const __attribute__((address_space(1))) unsigned int*)g,
      (__attribute__((address_space(3))) unsigned int*)l, 16, 0, 0);
}

__device__ __forceinline__ unsigned int cvtpk(float lo, float hi) {
  unsigned int r;
  asm("v_cvt_pk_bf16_f32 %0, %1, %2" : "=v"(r) : "v"(lo), "v"(hi));
  return r;
}

// ---------------- weight transpose: wT[m][d][c] = bf16(w_m[c][d]) ----------------
__global__ void k_wt(const float* __restrict__ wq, const float* __restrict__ wk,
                     const float* __restrict__ wv, const float* __restrict__ wp,
                     unsigned short* __restrict__ wT) {
  int m = blockIdx.x >> 8;
  int c = blockIdx.x & 255;
  const float* w = (m == 0) ? wq : (m == 1) ? wk : (m == 2) ? wv : wp;
  int d = threadIdx.x;
  wT[(size_t)(m * 256 + d) * 256 + c] = f2bf(w[c * 256 + d]);
}

// ---------------- GroupNorm stats (per batch over 1M elements) ----------------
__global__ void k_gn_part(const float* __restrict__ x, float2* __restrict__ part) {
  int b = blockIdx.x >> 5, seg = blockIdx.x & 31;
  const float4* xp = (const float4*)(x + ((size_t)b << 20) + ((size_t)seg << 15));
  float s = 0.f, sq = 0.f;
  for (int i = 0; i < 32; ++i) {
    float4 v = xp[threadIdx.x + i * 256];
    s += v.x + v.y + v.z + v.w;
    sq += v.x * v.x + v.y * v.y + v.z * v.z + v.w * v.w;
  }
  for (int m = 1; m <= 32; m <<= 1) { s += __shfl_xor(s, m); sq += __shfl_xor(sq, m); }
  __shared__ float2 red[4];
  int w = threadIdx.x >> 6;
  if ((threadIdx.x & 63) == 0) red[w] = make_float2(s, sq);
  __syncthreads();
  if (threadIdx.x == 0) {
    float S = 0.f, Q = 0.f;
    for (int i = 0; i < 4; ++i) { S += red[i].x; Q += red[i].y; }
    part[blockIdx.x] = make_float2(S, Q);
  }
}

__global__ void k_gn_stats(const float2* __restrict__ part, float2* __restrict__ stats) {
  int b = blockIdx.x, t = threadIdx.x;
  float s = 0.f, sq = 0.f;
  if (t < 32) { float2 p = part[b * 32 + t]; s = p.x; sq = p.y; }
  for (int m = 1; m <= 32; m <<= 1) { s += __shfl_xor(s, m); sq += __shfl_xor(sq, m); }
  if (t == 0) {
    float mean = s * (1.f / 1048576.f);
    float var = sq * (1.f / 1048576.f) - mean * mean;
    stats[b] = make_float2(mean, rsqrtf(var + 1e-3f));
  }
}

// ---------------- fused GN + QKV projection GEMM ----------------
__global__ __launch_bounds__(256) void k_qkv(
    const float* __restrict__ x, const float* __restrict__ gamma, const float* __restrict__ beta,
    const float* __restrict__ bq, const float* __restrict__ bk, const float* __restrict__ bv,
    const float2* __restrict__ stats, const unsigned short* __restrict__ wT,
    unsigned short* __restrict__ qo, unsigned short* __restrict__ ko, unsigned short* __restrict__ vo)
{
  __shared__ unsigned short As[128 * 64];
  __shared__ unsigned short Bs[128 * 64];
  const int bm = blockIdx.x, bn = blockIdx.y;
  const int mat = bn >> 1, dbase = (bn & 1) * 128;
  const int tid = threadIdx.x, lane = tid & 63, w = tid >> 6;
  const int wm = w >> 1, wn = w & 1;
  const int m0 = bm * 128;
  const float2 st = stats[bm >> 5];
  f32x16 acc[2][2] = {};
  for (int ks = 0; ks < 4; ++ks) {
    for (int i = 0; i < 8; ++i) {
      int chunk = tid + i * 256;
      int row = chunk >> 4, cq = (chunk & 15) * 4;
      int c = ks * 64 + cq;
      const float4 xv = *(const float4*)(x + (size_t)(m0 + row) * 256 + c);
      const float4 g = *(const float4*)(gamma + c);
      const float4 bt = *(const float4*)(beta + c);
      unsigned short h[4];
      h[0] = f2bf((xv.x - st.x) * st.y * g.x + bt.x);
      h[1] = f2bf((xv.y - st.x) * st.y * g.y + bt.y);
      h[2] = f2bf((xv.z - st.x) * st.y * g.z + bt.z);
      h[3] = f2bf((xv.w - st.x) * st.y * g.w + bt.w);
      *(uint2*)(&As[row * 64 + (cq ^ ((row & 7) << 3))]) = *(uint2*)h;
    }
    for (int i = 0; i < 4; ++i) {
      int chunk = tid + i * 256;
      int row = chunk >> 3, cc = (chunk & 7) * 8;
      const uint4* src = (const uint4*)(wT + (size_t)(mat * 256 + dbase + row) * 256 + ks * 64 + cc);
      *(uint4*)(&Bs[row * 64 + (cc ^ ((row & 7) << 3))]) = *src;
    }
    __syncthreads();
    for (int kk = 0; kk < 4; ++kk) {
      short8 a[2], b[2];
      for (int mi = 0; mi < 2; ++mi) {
        int row = wm * 64 + mi * 32 + (lane & 31);
        int off = (kk * 16 + (lane >> 5) * 8) ^ ((row & 7) << 3);
        a[mi] = *(const short8*)(&As[row * 64 + off]);
      }
      for (int ni = 0; ni < 2; ++ni) {
        int row = wn * 64 + ni * 32 + (lane & 31);
        int off = (kk * 16 + (lane >> 5) * 8) ^ ((row & 7) << 3);
        b[ni] = *(const short8*)(&Bs[row * 64 + off]);
      }
      for (int mi = 0; mi < 2; ++mi)
        for (int ni = 0; ni < 2; ++ni)
          acc[mi][ni] = __builtin_amdgcn_mfma_f32_32x32x16_bf16(a[mi], b[ni], acc[mi][ni], 0, 0, 0);
    }
    __syncthreads();
  }
  const float* bias = (mat == 0) ? bq : (mat == 1) ? bk : bv;
  unsigned short* outp = (mat == 0) ? qo : (mat == 1) ? ko : vo;
  const float qs = 0.09016844005555646f;  // (1/16) * log2(e)
  for (int ni = 0; ni < 2; ++ni) {
    int dcol = dbase + wn * 64 + ni * 32 + (lane & 31);
    float bv_ = bias[dcol];
    for (int mi = 0; mi < 2; ++mi)
      for (int r = 0; r < 16; ++r) {
        int rowD = (r & 3) + 8 * (r >> 2) + 4 * (lane >> 5);
        int token = m0 + wm * 64 + mi * 32 + rowD;
        float v = acc[mi][ni][r] + bv_;
        if (mat == 0) v *= qs;
        outp[(size_t)token * 256 + dcol] = f2bf(v);
      }
  }
}

// ---------------- V transpose: vt[b][d][n] = v[b][n][d] ----------------
__global__ __launch_bounds__(256) void k_vt(const unsigned short* __restrict__ v,
                                            unsigned short* __restrict__ vt) {
  __shared__ unsigned short T[64 * 64];
  int bx = blockIdx.x;
  int batch = bx >> 8;
  int tn = (bx & 255) >> 2, td = bx & 3;
  int n0 = tn * 64, d0 = td * 64;
  int tid = threadIdx.x;
  for (int i = 0; i < 2; ++i) {
    int chunk = tid + i * 256;
    int r = chunk >> 3, cc = (chunk & 7) * 8;
    const uint4* src = (const uint4*)(v + (size_t)(batch * 4096 + n0 + r) * 256 + d0 + cc);
    *(uint4*)(&T[r * 64 + (cc ^ ((r & 7) << 3))]) = *src;
  }
  __syncthreads();
  for (int i = 0; i < 2; ++i) {
    int chunk = tid + i * 256;
    int rd = chunk >> 3, cn = (chunk & 7) * 8;
    unsigned short tmp[8];
    for (int j = 0; j < 8; ++j) {
      int nn = cn + j;
      tmp[j] = T[nn * 64 + (rd ^ ((nn & 7) << 3))];
    }
    *(uint4*)(vt + (size_t)(batch * 256 + d0 + rd) * 4096 + n0 + cn) = *(uint4*)tmp;
  }
}

// ---------------- flash attention, kv-split, 32q/wave, double-buffered ----------------
// 512 blocks (2/CU): g=blockIdx&15 -> (batch,half) pinned per XCD; qt=blockIdx>>4
// (32 tiles of 128 q-rows). 4 waves x 32 q-rows (2 q-frags). KVBLK=32 double-
// buffered: STAGE(t+1) issued right after the single __syncthreads()/iter, so
// its implicit vmcnt(0) at the *next* barrier waits on loads a full iteration
// old. Swapped QK^T, in-register P via cvt_pk+bpermute. Each K/V ds_read feeds
// 2 MFMAs (halves the LDS-BW floor vs round 2). Coalesced partial stores via
// LDS transpose in the epilogue.
__global__ __launch_bounds__(256, 2) void k_attn(
    const unsigned short* __restrict__ q, const unsigned short* __restrict__ k,
    const unsigned short* __restrict__ vt,
    unsigned short* __restrict__ part0, unsigned short* __restrict__ part1,
    float2* __restrict__ ml)
{
  __shared__ unsigned short Ks0[32 * 256], Ks1[32 * 256];
  __shared__ unsigned short Vt0[256 * 32], Vt1[256 * 32];
  const int g = blockIdx.x & 15, qt = blockIdx.x >> 4;
  const int batch = g >> 1, half = g & 1;
  const int q0 = qt * 128;
  const int tid = threadIdx.x, lane = tid & 63, li = lane & 15, hi = lane >> 4, w = tid >> 6;

  short8 qf[2][8];
#pragma unroll
  for (int qs = 0; qs < 2; ++qs) {
    const size_t qtok = (size_t)(batch * 4096 + q0 + w * 32 + qs * 16 + li);
#pragma unroll
    for (int kt = 0; kt < 8; ++kt)
      qf[qs][kt] = *(const short8*)(q + qtok * 256 + kt * 32 + hi * 8);
  }
  f32x4 acc[2][16] = {};
  float m_r[2] = {-INFINITY, -INFINITY};
  float l_r[2] = {0.f, 0.f};
  // bpermute source-lane byte indices: pull from lane ((2*hi+b)&3)*16+li
  const int idx0 = ((((hi << 1) + 0) & 3) * 16 + li) << 2;
  const int idx1 = ((((hi << 1) + 1) & 3) * 16 + li) << 2;

  // iter-invariant staging offsets (source pre-swizzled; LDS dest linear)
  unsigned koff[4], voff[4];
#pragma unroll
  for (int i = 0; i < 4; ++i) {
    int krow = w * 8 + i * 2 + (lane >> 5);            // 0..31
    koff[i] = krow * 256 + (((lane & 31) ^ (krow & 7)) << 3);
    int vrow = w * 64 + i * 16 + (lane >> 2);          // 0..255 (d)
    voff[i] = vrow * 4096 + (((lane & 3) ^ (vrow & 3)) << 3);
  }
  const unsigned short* kb = k + ((size_t)batch * 4096 + half * 2048) * 256;
  const unsigned short* vb = vt + (size_t)batch * 256 * 4096 + half * 2048;

#define STAGE(KD, VD) do {                                   \
    _Pragma("unroll")                                        \
    for (int i = 0; i < 4; ++i)                              \
      gl_lds16(kb + koff[i], &KD[(w * 8 + i * 2) * 256]);    \
    _Pragma("unroll")                                        \
    for (int i = 0; i < 4; ++i)                              \
      gl_lds16(vb + (size_t)voff[i], &VD[(w * 64 + i * 16) * 32]); \
  } while (0)

  STAGE(Ks0, Vt0);
  for (int it = 0; it < 64; ++it) {
    const int cur = it & 1;
    __syncthreads();  // iter-(it-1) reads done AND stage(tile it) drained
    if (it < 63) {
      kb += 32 * 256;
      vb += 32;
      if (cur) STAGE(Ks0, Vt0); else STAGE(Ks1, Vt1);  // tile it+1 -> other buf
    }
    const unsigned short* Kc = cur ? Ks1 : Ks0;
    const unsigned short* Vc = cur ? Vt1 : Vt0;
    // S^T = K Q^T : s[qs][ct][r] = S[kv=ct*16+hi*4+r][q]
    f32x4 s[2][2] = {};
    __builtin_amdgcn_s_setprio(1);
#pragma unroll
    for (int ct = 0; ct < 2; ++ct)
#pragma unroll
      for (int kt = 0; kt < 8; ++kt) {
        int rowK = ct * 16 + li;
        int off = (kt * 32 + hi * 8) ^ ((li & 7) << 3);
        short8 kf = *(const short8*)(&Kc[rowK * 256 + off]);
        s[0][ct] = __builtin_amdgcn_mfma_f32_16x16x32_bf16(kf, qf[0][kt], s[0][ct], 0, 0, 0);
        s[1][ct] = __builtin_amdgcn_mfma_f32_16x16x32_bf16(kf, qf[1][kt], s[1][ct], 0, 0, 0);
      }
    __builtin_amdgcn_s_setprio(0);
    // row-local online softmax (each lane owns q-col li of both q-frags)
    float pm[2];
#pragma unroll
    for (int qs = 0; qs < 2; ++qs) {
      float p = fmaxf(fmaxf(fmaxf(s[qs][0][0], s[qs][0][1]), fmaxf(s[qs][0][2], s[qs][0][3])),
                      fmaxf(fmaxf(s[qs][1][0], s[qs][1][1]), fmaxf(s[qs][1][2], s[qs][1][3])));
      p = fmaxf(p, __shfl_xor(p, 16));
      p = fmaxf(p, __shfl_xor(p, 32));
      pm[qs] = p;
    }
    if (!__all(fmaxf(pm[0] - m_r[0], pm[1] - m_r[1]) <= 8.0f)) {  // defer-max
#pragma unroll
      for (int qs = 0; qs < 2; ++qs) {
        float mn = fmaxf(m_r[qs], pm[qs]);
        float corr = exp2f(m_r[qs] - mn);
        m_r[qs] = mn;
        l_r[qs] *= corr;
        float cq[4];
#pragma unroll
        for (int r = 0; r < 4; ++r) cq[r] = __shfl(corr, hi * 4 + r);
#pragma unroll
        for (int dt = 0; dt < 16; ++dt)
#pragma unroll
          for (int r = 0; r < 4; ++r) acc[qs][dt][r] *= cq[r];
      }
    }
    short8 pf[2];
#pragma unroll
    for (int qs = 0; qs < 2; ++qs) {
      float rs = 0.f;
#pragma unroll
      for (int ct = 0; ct < 2; ++ct)
#pragma unroll
        for (int r = 0; r < 4; ++r) {
          float p = exp2f(s[qs][ct][r] - m_r[qs]);
          s[qs][ct][r] = p;
          rs += p;
        }
      rs += __shfl_xor(rs, 16);
      rs += __shfl_xor(rs, 32);
      l_r[qs] += rs;
      unsigned int pk00 = cvtpk(s[qs][0][0], s[qs][0][1]), pk01 = cvtpk(s[qs][0][2], s[qs][0][3]);
      unsigned int pk10 = cvtpk(s[qs][1][0], s[qs][1][1]), pk11 = cvtpk(s[qs][1][2], s[qs][1][3]);
      int w0a = __builtin_amdgcn_ds_bpermute(idx0, (int)pk00);
      int w0b = __builtin_amdgcn_ds_bpermute(idx0, (int)pk10);
      int w1a = __builtin_amdgcn_ds_bpermute(idx0, (int)pk01);
      int w1b = __builtin_amdgcn_ds_bpermute(idx0, (int)pk11);
      int w2a = __builtin_amdgcn_ds_bpermute(idx1, (int)pk00);
      int w2b = __builtin_amdgcn_ds_bpermute(idx1, (int)pk10);
      int w3a = __builtin_amdgcn_ds_bpermute(idx1, (int)pk01);
      int w3b = __builtin_amdgcn_ds_bpermute(idx1, (int)pk11);
      bool sel = (lane & 32) != 0;
      int4 pw = { sel ? w0b : w0a, sel ? w1b : w1a, sel ? w2b : w2a, sel ? w3b : w3a };
      pf[qs] = __builtin_bit_cast(short8, pw);
    }
    // O += P V : acc[qs][dt] over d = dt*16+li, q = hi*4+r
    __builtin_amdgcn_s_setprio(1);
#pragma unroll
    for (int dt = 0; dt < 16; ++dt) {
      int rowd = dt * 16 + li;
      int off = (hi * 8) ^ ((li & 3) << 3);
      short8 vf = *(const short8*)(&Vc[rowd * 32 + off]);
      acc[0][dt] = __builtin_amdgcn_mfma_f32_16x16x32_bf16(pf[0], vf, acc[0][dt], 0, 0, 0);
      acc[1][dt] = __builtin_amdgcn_mfma_f32_16x16x32_bf16(pf[1], vf, acc[1][dt], 0, 0, 0);
    }
    __builtin_amdgcn_s_setprio(0);
  }
#undef STAGE
  __syncthreads();  // all waves done with final tile before LDS reuse
  // (m,l): lanes 0..15 hold q-col = lane for both q-frags
  if (lane < 16) {
#pragma unroll
    for (int qs = 0; qs < 2; ++qs)
      ml[half * 32768 + (size_t)batch * 4096 + q0 + w * 32 + qs * 16 + lane] =
          make_float2(m_r[qs], l_r[qs]);
  }
  // transpose acc through per-wave LDS region (8192 ushorts each), coalesced store
  unsigned short* Lw = (w == 0) ? Ks0 : (w == 1) ? Ks1 : (w == 2) ? Vt0 : Vt1;
#pragma unroll
  for (int qs = 0; qs < 2; ++qs)
#pragma unroll
    for (int dt = 0; dt < 16; ++dt)
#pragma unroll
      for (int r = 0; r < 4; ++r)
        Lw[(qs * 16 + hi * 4 + r) * 256 + dt * 16 + li] = f2bf(acc[qs][dt][r]);
  unsigned short* pout = (half ? part1 : part0) + ((size_t)batch * 4096 + q0 + w * 32) * 256;
#pragma unroll
  for (int i = 0; i < 16; ++i) {
    short8 v = *(const short8*)(&Lw[i * 512 + lane * 8]);
    int row = i * 2 + (lane >> 5);
    *(short8*)(pout + row * 256 + (lane & 31) * 8) = v;
  }
}

// ---------------- merge kv-split halves ----------------
__global__ __launch_bounds__(256) void k_merge(
    const unsigned short* __restrict__ p0, const unsigned short* __restrict__ p1,
    const float2* __restrict__ ml, unsigned short* __restrict__ o)
{
  int tid = threadIdx.x;
  int tok = blockIdx.x * 8 + (tid >> 5);
  int d0 = (tid & 31) * 8;
  float2 a = ml[tok];
  float2 b = ml[32768 + tok];
  float m = fmaxf(a.x, b.x);
  float s0 = exp2f(a.x - m), s1 = exp2f(b.x - m);
  float r0 = s0 / (s0 * a.y + s1 * b.y);
  float r1 = s1 / (s0 * a.y + s1 * b.y);
  short8 u0 = *(const short8*)(p0 + (size_t)tok * 256 + d0);
  short8 u1 = *(const short8*)(p1 + (size_t)tok * 256 + d0);
  unsigned short r[8];
  for (int j = 0; j < 8; ++j)
    r[j] = f2bf(r0 * bf2f((unsigned short)u0[j]) + r1 * bf2f((unsigned short)u1[j]));
  *(short8*)(o + (size_t)tok * 256 + d0) = *(short8*)r;
}

// ---------------- output projection + bias + residual ----------------
__global__ __launch_bounds__(256) void k_proj(
    const unsigned short* __restrict__ o, const unsigned short* __restrict__ wT,
    const float* __restrict__ bp, const float* __restrict__ x, float* __restrict__ out)
{
  __shared__ unsigned short As[128 * 64];
  __shared__ unsigned short Bs[128 * 64];
  const int bm = blockIdx.x, bn = blockIdx.y;
  const int dbase = bn * 128;
  const int tid = threadIdx.x, lane = tid & 63, w = tid >> 6;
  const int wm = w >> 1, wn = w & 1;
  const int m0 = bm * 128;
  f32x16 acc[2][2] = {};
  for (int ks = 0; ks < 4; ++ks) {
    for (int i = 0; i < 4; ++i) {
      int chunk = tid + i * 256;
      int row = chunk >> 3, cc = (chunk & 7) * 8;
      const uint4* src = (const uint4*)(o + (size_t)(m0 + row) * 256 + ks * 64 + cc);
      *(uint4*)(&As[row * 64 + (cc ^ ((row & 7) << 3))]) = *src;
    }
    for (int i = 0; i < 4; ++i) {
      int chunk = tid + i * 256;
      int row = chunk >> 3, cc = (chunk & 7) * 8;
      const uint4* src = (const uint4*)(wT + (size_t)(3 * 256 + dbase + row) * 256 + ks * 64 + cc);
      *(uint4*)(&Bs[row * 64 + (cc ^ ((row & 7) << 3))]) = *src;
    }
    __syncthreads();
    for (int kk = 0; kk < 4; ++kk) {
      short8 a[2], b[2];
      for (int mi = 0; mi < 2; ++mi) {
        int row = wm * 64 + mi * 32 + (lane & 31);
        int off = (kk * 16 + (lane >> 5) * 8) ^ ((row & 7) << 3);
        a[mi] = *(const short8*)(&As[row * 64 + off]);
      }
      for (int ni = 0; ni < 2; ++ni) {
        int row = wn * 64 + ni * 32 + (lane & 31);
        int off = (kk * 16 + (lane >> 5) * 8) ^ ((row & 7) << 3);
        b[ni] = *(const short8*)(&Bs[row * 64 + off]);
      }
      for (int mi = 0; mi < 2; ++mi)
        for (int ni = 0; ni < 2; ++ni)
          acc[mi][ni] = __builtin_amdgcn_mfma_f32_32x32x16_bf16(a[mi], b[ni], acc[mi][ni], 0, 0, 0);
    }
    __syncthreads();
  }
  for (int ni = 0; ni < 2; ++ni) {
    int dcol = dbase + wn * 64 + ni * 32 + (lane & 31);
    float bv_ = bp[dcol];
    for (int mi = 0; mi < 2; ++mi)
      for (int r = 0; r < 16; ++r) {
        int rowD = (r & 3) + 8 * (r >> 2) + 4 * (lane >> 5);
        size_t idx = (size_t)(m0 + wm * 64 + mi * 32 + rowD) * 256 + dcol;
        out[idx] = x[idx] + acc[mi][ni][r] + bv_;
      }
  }
}

extern "C" void kernel_launch(void* const* d_in, const int* in_sizes, int n_in,
                              void* d_out, int out_size, void* d_ws, size_t ws_size,
                              hipStream_t stream) {
  const float* x = (const float*)d_in[0];
  const float* gamma = (const float*)d_in[1];
  const float* beta = (const float*)d_in[2];
  const float* wq = (const float*)d_in[3];
  const float* bq = (const float*)d_in[4];
  const float* wk = (const float*)d_in[5];
  const float* bk = (const float*)d_in[6];
  const float* wv = (const float*)d_in[7];
  const float* bv = (const float*)d_in[8];
  const float* wp = (const float*)d_in[9];
  const float* bp = (const float*)d_in[10];
  char* ws = (char*)d_ws;
  float2* part = (float2*)(ws + WS_PART);
  float2* stats = (float2*)(ws + WS_STATS);
  unsigned short* wT = (unsigned short*)(ws + WS_WT);
  float2* mlw = (float2*)(ws + WS_ML);
  unsigned short* qw = (unsigned short*)(ws + WS_Q);
  unsigned short* kw = (unsigned short*)(ws + WS_K);
  unsigned short* vw = (unsigned short*)(ws + WS_V);
  unsigned short* vtw = (unsigned short*)(ws + WS_VT);
  unsigned short* ow = (unsigned short*)(ws + WS_O);
  float* out = (float*)d_out;

  k_wt<<<1024, 256, 0, stream>>>(wq, wk, wv, wp, wT);
  k_gn_part<<<256, 256, 0, stream>>>(x, part);
  k_gn_stats<<<8, 64, 0, stream>>>(part, stats);
  k_qkv<<<dim3(256, 6), 256, 0, stream>>>(x, gamma, beta, bq, bk, bv, stats, wT, qw, kw, vw);
  k_vt<<<2048, 256, 0, stream>>>(vw, vtw);
  // partial0 overwrites V (dead after k_vt), partial1 overwrites O region
  k_attn<<<512, 256, 0, stream>>>(qw, kw, vtw, vw, ow, mlw);
  // merged O overwrites Q (dead after k_attn)
  k_merge<<<4096, 256, 0, stream>>>(vw, ow, mlw, qw);
  k_proj<<<dim3(256, 2), 256, 0, stream>>>(qw, wT, bp, x, out);
}